// Round 9
// baseline (138.003 us; speedup 1.0000x reference)
//
#include <hip/hip_runtime.h>

#define LSEQ 1024
#define NB   2
#define NH   8
#define DD   64
#define DMOD 768

using bf16x8 = __attribute__((ext_vector_type(8))) short;
using f32x4  = __attribute__((ext_vector_type(4))) float;

__device__ inline unsigned short f2bf(float f) {
    union { float f; unsigned u; } v; v.f = f;
    unsigned r = v.u + 0x7FFFu + ((v.u >> 16) & 1u);
    return (unsigned short)(r >> 16);
}

// async global->LDS, 16B per lane. LDS dest is wave-uniform base + lane*16.
__device__ __forceinline__ void glds16(const unsigned short* g, unsigned short* l) {
    __builtin_amdgcn_global_load_lds(
        (const __attribute__((address_space(1))) void*)g,
        (__attribute__((address_space(3))) void*)l, 16, 0, 0);
}

// ---------------------------------------------------------------------------
// blocks 0..3071: pack x + Wq|Wk|Wv + Wo to bf16 (streaming)
// block  3072   : cls LUT (2048 u8)
// blocks 3073..3080: per-head wsfx[h][n] = (suffix(v.w_pos)-suffix(u.w_pos))/8
// ---------------------------------------------------------------------------
__global__ __launch_bounds__(256) void pack_setup(
    const float4* __restrict__ x,  const float4* __restrict__ wq,
    const float4* __restrict__ wk, const float4* __restrict__ wv,
    const float4* __restrict__ wo,
    const float* __restrict__ u_bias, const float* __restrict__ v_bias,
    const float* __restrict__ w_pos,
    ushort4* __restrict__ xb, ushort4* __restrict__ wqb, ushort4* __restrict__ wkb,
    ushort4* __restrict__ wvb, ushort4* __restrict__ wob,
    float* __restrict__ wsfx, unsigned char* __restrict__ cls_g)
{
    int tid = threadIdx.x;
    if (blockIdx.x >= 3072) {
        int sb = blockIdx.x - 3072;
        if (sb == 0) {
            // cls LUT
            __shared__ float w_s[32];
            __shared__ int cmin_s[1024];
            if (tid < 32) {
                float pr = expf(logf(512.5f) / 32.0f);
                w_s[tid] = powf(pr, (float)(tid + 1));
            }
            __syncthreads();
            for (int d = tid; d < 1024; d += 256) {
                float fd = (float)d;
                int cm = 32;
                for (int c = 31; c >= 0; --c) if (fd <= w_s[c]) cm = c;
                cmin_s[d] = cm;
            }
            __syncthreads();
            for (int d2 = tid; d2 < 2048; d2 += 256) {
                int dd = d2 - 1023;
                int ad = dd < 0 ? -dd : dd; if (ad > 1023) ad = 1023;
                int t = (dd < 0) ? 0 : ((dd == 0) ? 1 : 2);
                cls_g[d2] = (unsigned char)(t * 33 + cmin_s[ad]);
            }
        } else {
            // per-head wsfx
            int h = sb - 1;
            __shared__ float vred[4][64];
            __shared__ float ured[4][64];
            __shared__ float wd[64];
            int n = tid & 63, g = tid >> 6;
            float vs = 0.f, us = 0.f;
#pragma unroll
            for (int k = 0; k < 16; ++k) {
                int d = g * 16 + k;
                float wp = w_pos[(h * 64 + d) * 64 + n];
                vs += v_bias[h * 64 + d] * wp;
                us += u_bias[h * 64 + d] * wp;
            }
            vred[g][n] = vs; ured[g][n] = us;
            __syncthreads();
            if (tid < 64) {
                float v4 = vred[0][tid] + vred[1][tid] + vred[2][tid] + vred[3][tid];
                float u4 = ured[0][tid] + ured[1][tid] + ured[2][tid] + ured[3][tid];
                wd[tid] = v4 - u4;
            }
            __syncthreads();
            if (tid < 64) {
                int nn = tid & 31, cb = tid & 32;
                float s = 0.f;
                for (int c = 31; c >= nn; --c) s += wd[cb + c];
                wsfx[h * 64 + tid] = s * 0.125f;
            }
        }
        return;
    }
    int i = blockIdx.x * 256 + tid;
    const float4* src; ushort4* dst; int off;
    if (i < 393216)      { src = x;  dst = xb;  off = i; }
    else if (i < 491520) { src = wq; dst = wqb; off = i - 393216; }
    else if (i < 589824) { src = wk; dst = wkb; off = i - 491520; }
    else if (i < 688128) { src = wv; dst = wvb; off = i - 589824; }
    else                 { src = wo; dst = wob; off = i - 688128; }
    float4 v = src[off];
    ushort4 o;
    o.x = f2bf(v.x); o.y = f2bf(v.y); o.z = f2bf(v.z); o.w = f2bf(v.w);
    dst[off] = o;
}

// ---------------------------------------------------------------------------
// fused QKV projection GEMM: [2048x768] @ [1536x768]^T, 64x64 tile, 4 waves.
// Staging via global_load_lds width=16 with BOTH-SIDES XOR swizzle (rule #21).
// One barrier per K-step=64; next tile's DMA in flight under 8 MFMA/wave.
// ---------------------------------------------------------------------------
__global__ __launch_bounds__(256) void gemm_qkv(
    const unsigned short* __restrict__ X, const unsigned short* __restrict__ W,
    const float* __restrict__ ub,
    unsigned short* __restrict__ Qb, unsigned short* __restrict__ Kb,
    unsigned short* __restrict__ Vtb)
{
    __shared__ __align__(16) unsigned short Xs[2][64][64];
    __shared__ __align__(16) unsigned short Wsm[2][64][64];
    __shared__ __align__(16) unsigned short Ct[64][72];

    int tid = threadIdx.x;
    int w = tid >> 6, lane = tid & 63, l15 = lane & 15, q = lane >> 4;
    int M0 = blockIdx.y * 64, N0 = blockIdx.x * 64;

    int sr = lane >> 3;                        // == dest row & 7
    int scol = ((lane & 7) * 8) ^ (sr << 3);   // shorts
    const unsigned short* xg = X + (size_t)(M0 + w * 8 + sr) * 768 + scol;
    const unsigned short* wg = W + (size_t)(N0 + w * 8 + sr) * 768 + scol;
    unsigned short* XsF = &Xs[0][0][0];
    unsigned short* WsF = &Wsm[0][0][0];
    int wb = w * 512;   // wave-uniform LDS short offset

#define ISSUE(K, BUF) do { \
    glds16(xg + (K),             XsF + (BUF) * 4096 + wb); \
    glds16(xg + 32 * 768 + (K),  XsF + (BUF) * 4096 + 2048 + wb); \
    glds16(wg + (K),             WsF + (BUF) * 4096 + wb); \
    glds16(wg + 32 * 768 + (K),  WsF + (BUF) * 4096 + 2048 + wb); \
} while (0)

    ISSUE(0, 0);

    int rswz = (l15 & 7) << 3;                 // read-side XOR (shorts)
    f32x4 acc[4] = {};
    int cur = 0;
    for (int k0 = 0; k0 < 768; k0 += 64) {
        __syncthreads();                 // vmcnt drain -> buf[cur] ready
        if (k0 + 64 < 768) ISSUE(k0 + 64, cur ^ 1);   // async, hides under MFMA
        bf16x8 a0 = *(bf16x8*)&Xs[cur][w * 16 + l15][(q * 8) ^ rswz];
        bf16x8 a1 = *(bf16x8*)&Xs[cur][w * 16 + l15][(32 + q * 8) ^ rswz];
#pragma unroll
        for (int ct = 0; ct < 4; ++ct) {
            bf16x8 b0 = *(bf16x8*)&Wsm[cur][ct * 16 + l15][(q * 8) ^ rswz];
            bf16x8 b1 = *(bf16x8*)&Wsm[cur][ct * 16 + l15][(32 + q * 8) ^ rswz];
            acc[ct] = __builtin_amdgcn_mfma_f32_16x16x32_bf16(a0, b0, acc[ct], 0, 0, 0);
            acc[ct] = __builtin_amdgcn_mfma_f32_16x16x32_bf16(a1, b1, acc[ct], 0, 0, 0);
        }
        cur ^= 1;
    }
#undef ISSUE

    if (N0 < 1024) {
        int isQ = (N0 < 512);
#pragma unroll
        for (int ct = 0; ct < 4; ++ct) {
            float u0 = isQ ? ub[N0 + ct * 16 + l15] : 0.f;
            float sc = isQ ? 0.125f : 1.0f;
#pragma unroll
            for (int r = 0; r < 4; ++r)
                Ct[w * 16 + q * 4 + r][ct * 16 + l15] = f2bf((acc[ct][r] + u0) * sc);
        }
        __syncthreads();
        int Nh = isQ ? N0 : (N0 - 512);
        unsigned short* out = isQ ? Qb : Kb;
        size_t base = ((size_t)((M0 >> 10) * 8 + (Nh >> 6)) * 1024 + (M0 & 1023)) * 64;
#pragma unroll
        for (int it = 0; it < 2; ++it) {
            int idx = tid + it * 256;
            int row = idx >> 3, sg = idx & 7;
            *(uint4*)(out + base + (size_t)row * 64 + sg * 8) = *(uint4*)&Ct[row][sg * 8];
        }
    } else {
#pragma unroll
        for (int ct = 0; ct < 4; ++ct) {
            ushort4 pk;
            pk.x = f2bf(acc[ct][0]); pk.y = f2bf(acc[ct][1]);
            pk.z = f2bf(acc[ct][2]); pk.w = f2bf(acc[ct][3]);
            *(ushort4*)&Ct[ct * 16 + l15][w * 16 + q * 4] = pk;   // [d][j]
        }
        __syncthreads();
        size_t base = ((size_t)((M0 >> 10) * 8 + ((N0 - 1024) >> 6))) * 65536;
        int j0 = M0 & 1023;
#pragma unroll
        for (int it = 0; it < 2; ++it) {
            int idx = tid + it * 256;
            int d = idx >> 3, sg = idx & 7;
            *(uint4*)(Vtb + base + (size_t)d * 1024 + j0 + sg * 8) = *(uint4*)&Ct[d][sg * 8];
        }
    }
}

// ---------------------------------------------------------------------------
// out-projection GEMM: fp32 out [2048][768] = aob[2048][512] @ Wo[768][512]^T
// + bo. Same swizzled global_load_lds staging, K-step 64, 8 iterations.
// ---------------------------------------------------------------------------
__global__ __launch_bounds__(256) void gemm_o(
    const unsigned short* __restrict__ X, const unsigned short* __restrict__ W,
    const float* __restrict__ bias, float* __restrict__ out)
{
    __shared__ __align__(16) unsigned short Xs[2][64][64];
    __shared__ __align__(16) unsigned short Wsm[2][64][64];
    __shared__ __align__(16) float Ctf[64][72];

    int tid = threadIdx.x;
    int w = tid >> 6, lane = tid & 63, l15 = lane & 15, q = lane >> 4;
    int M0 = blockIdx.y * 64, N0 = blockIdx.x * 64;

    int sr = lane >> 3;
    int scol = ((lane & 7) * 8) ^ (sr << 3);
    const unsigned short* xg = X + (size_t)(M0 + w * 8 + sr) * 512 + scol;
    const unsigned short* wg = W + (size_t)(N0 + w * 8 + sr) * 512 + scol;
    unsigned short* XsF = &Xs[0][0][0];
    unsigned short* WsF = &Wsm[0][0][0];
    int wb = w * 512;

#define ISSUEO(K, BUF) do { \
    glds16(xg + (K),             XsF + (BUF) * 4096 + wb); \
    glds16(xg + 32 * 512 + (K),  XsF + (BUF) * 4096 + 2048 + wb); \
    glds16(wg + (K),             WsF + (BUF) * 4096 + wb); \
    glds16(wg + 32 * 512 + (K),  WsF + (BUF) * 4096 + 2048 + wb); \
} while (0)

    ISSUEO(0, 0);

    int rswz = (l15 & 7) << 3;
    f32x4 acc[4] = {};
    int cur = 0;
    for (int k0 = 0; k0 < 512; k0 += 64) {
        __syncthreads();
        if (k0 + 64 < 512) ISSUEO(k0 + 64, cur ^ 1);
        bf16x8 a0 = *(bf16x8*)&Xs[cur][w * 16 + l15][(q * 8) ^ rswz];
        bf16x8 a1 = *(bf16x8*)&Xs[cur][w * 16 + l15][(32 + q * 8) ^ rswz];
#pragma unroll
        for (int ct = 0; ct < 4; ++ct) {
            bf16x8 b0 = *(bf16x8*)&Wsm[cur][ct * 16 + l15][(q * 8) ^ rswz];
            bf16x8 b1 = *(bf16x8*)&Wsm[cur][ct * 16 + l15][(32 + q * 8) ^ rswz];
            acc[ct] = __builtin_amdgcn_mfma_f32_16x16x32_bf16(a0, b0, acc[ct], 0, 0, 0);
            acc[ct] = __builtin_amdgcn_mfma_f32_16x16x32_bf16(a1, b1, acc[ct], 0, 0, 0);
        }
        cur ^= 1;
    }
#undef ISSUEO

#pragma unroll
    for (int ct = 0; ct < 4; ++ct) {
        float bv = bias[N0 + ct * 16 + l15];
#pragma unroll
        for (int r = 0; r < 4; ++r)
            Ctf[w * 16 + q * 4 + r][ct * 16 + l15] = acc[ct][r] + bv;
    }
    __syncthreads();
#pragma unroll
    for (int it = 0; it < 4; ++it) {
        int idx = tid + it * 256;
        int row = idx >> 4, sg = idx & 15;
        *(float4*)(out + (size_t)(M0 + row) * 768 + N0 + sg * 4) = *(float4*)&Ctf[row][sg * 4];
    }
}

// ---------------------------------------------------------------------------
// MFMA flash attention, 8-wave blocks (512 thr): 1024 blocks x 8 waves ->
// 32 waves/CU (was 16; R7 showed Occupancy 38.7%, all pipes idle ->
// latency-bound). Each wave covers a j-eighth (2 jt of 64). Inner code is
// R1/R7-exact. LDS via typed union (compiler-managed); Pl rows padded to 80
// shorts so all Pl accesses are 16B-aligned. No inline asm.
// ---------------------------------------------------------------------------
__global__ __launch_bounds__(512, 8) void attn_mfma(
    const unsigned short* __restrict__ Qbf,   // [bh][i][d] bf16 ((q+u)/8)
    const unsigned short* __restrict__ Kbf,   // [bh][j][d] bf16
    const unsigned short* __restrict__ Vt,    // [bh][d][j] bf16
    const float* __restrict__ w_pos,          // [h][d][n] fp32
    const float* __restrict__ wsfx,           // [h][64]  (vsfx-usfx)/8
    const unsigned char* __restrict__ cls_g,
    unsigned short* __restrict__ ao)          // [b*1024+i][h*64+d] bf16
{
    __shared__ float biasT[16 * 99];
    __shared__ __align__(8) unsigned char cls[2048];
    union Ovl {
        unsigned short Pl[8][16][80];                                   // 20480 B (K-loop)
        struct { unsigned short wptS[64][68]; float qwL[16][68]; } pre; // 13056 B (preamble)
        struct { float Obuf[4][64][17]; float lbuf[4][16]; } post;      // 17664 B (epilogue)
    };
    __shared__ Ovl ovl;

    int tid = threadIdx.x;
    int b = blockIdx.z, h = blockIdx.y, bh = b * 8 + h;
    int i0 = blockIdx.x * 16;
    int w = tid >> 6, lane = tid & 63, l15 = lane & 15, q = lane >> 4;

    ((unsigned int*)cls)[tid] = ((const unsigned int*)cls_g)[tid];
    // stage w_pos[h] (fp32 [d][n]) -> bf16 transposed wptS[n][d], padded rows
    {
        const float4* wsrc = (const float4*)(w_pos + h * 4096);
#pragma unroll
        for (int it = 0; it < 2; ++it) {
            int f = tid + it * 512;          // float4 index, 0..1023
            float4 wv = wsrc[f];
            int d = f >> 4, n4 = (f & 15) * 4;
            ovl.pre.wptS[n4 + 0][d] = f2bf(wv.x);
            ovl.pre.wptS[n4 + 1][d] = f2bf(wv.y);
            ovl.pre.wptS[n4 + 2][d] = f2bf(wv.z);
            ovl.pre.wptS[n4 + 3][d] = f2bf(wv.w);
        }
    }

    int ig = i0 + l15;
    const unsigned short* qrow = Qbf + ((size_t)bh * 1024 + ig) * 64;
    bf16x8 qf0 = *(const bf16x8*)(qrow + q * 8);
    bf16x8 qf1 = *(const bf16x8*)(qrow + 32 + q * 8);
    __syncthreads();

    // qw MFMA: waves 0..3, wave w covers n = w*16 .. w*16+15
    if (w < 4) {
        bf16x8 b0 = *(bf16x8*)&ovl.pre.wptS[w * 16 + l15][q * 8];
        bf16x8 b1 = *(bf16x8*)&ovl.pre.wptS[w * 16 + l15][32 + q * 8];
        f32x4 a = {};
        a = __builtin_amdgcn_mfma_f32_16x16x32_bf16(qf0, b0, a, 0, 0, 0);
        a = __builtin_amdgcn_mfma_f32_16x16x32_bf16(qf1, b1, a, 0, 0, 0);
#pragma unroll
        for (int r = 0; r < 4; ++r)
            ovl.pre.qwL[q * 4 + r][w * 16 + l15] = a[r];
    }
    __syncthreads();

    // suffix-scan halves (fixed 32 iters, broadcast reads) + add wsfx.
    // Each row il is handled entirely by one wave -> race-free in-place.
    const float* wsh = wsfx + h * 64;
#pragma unroll
    for (int it = 0; it < 2; ++it) {
        int idx = tid + it * 512;
        int il = idx >> 6, n = idx & 63, nn = n & 31, cb = n & 32;
        float run = 0.f, s = 0.f;
#pragma unroll
        for (int c = 31; c >= 0; --c) {
            run += ovl.pre.qwL[il][cb + c];
            if (c == nn) s = run;
        }
        ovl.pre.qwL[il][n] = s + wsh[n];
    }
    __syncthreads();

    for (int idx = tid; idx < 528; idx += 512) {
        int il = idx / 33, c = idx - il * 33;
        float up = 0.f, sp = 0.f;
        if (c < 32) {
            up = ovl.pre.qwL[il][c];
            sp = ovl.pre.qwL[il][32 + c];
        }
        float* bt = biasT + il * 99;
        bt[c]      = up - sp;   // dd < 0
        bt[33 + c] = up;        // dd == 0
        bt[66 + c] = up + sp;   // dd > 0
    }
    __syncthreads();

    const unsigned short* Kbase = Kbf + (size_t)bh * 65536;
    const unsigned short* Vbase = Vt  + (size_t)bh * 65536;
    const float* btrow = biasT + l15 * 99;
    int clsoff = 1023 - ig;

    f32x4 Oacc[4] = {};
    float lsum = 0.f;

    for (int jt = 0; jt < 2; ++jt) {
        int jb = w * 128 + jt * 64;
        f32x4 st[4];
        __builtin_amdgcn_s_setprio(1);
#pragma unroll
        for (int ct = 0; ct < 4; ++ct) {
            const unsigned short* krow = Kbase + (size_t)(jb + ct * 16 + l15) * 64;
            bf16x8 ka0 = *(const bf16x8*)(krow + q * 8);
            bf16x8 ka1 = *(const bf16x8*)(krow + 32 + q * 8);
            f32x4 a = {};
            a = __builtin_amdgcn_mfma_f32_16x16x32_bf16(ka0, qf0, a, 0, 0, 0);
            a = __builtin_amdgcn_mfma_f32_16x16x32_bf16(ka1, qf1, a, 0, 0, 0);
            st[ct] = a;
        }
        __builtin_amdgcn_s_setprio(0);
#pragma unroll
        for (int ct = 0; ct < 4; ++ct) {
            int d2b = jb + ct * 16 + q * 4 + clsoff;
            float pv[4];
#pragma unroll
            for (int r = 0; r < 4; ++r) {
                float s = st[ct][r] + btrow[cls[d2b + r]];
                float p = __expf(s);
                lsum += p;
                pv[r] = p;
            }
            ushort4 pk;
            pk.x = f2bf(pv[0]); pk.y = f2bf(pv[1]);
            pk.z = f2bf(pv[2]); pk.w = f2bf(pv[3]);
            *(ushort4*)&ovl.Pl[w][l15][ct * 16 + q * 4] = pk;
        }
        __builtin_amdgcn_s_setprio(1);
#pragma unroll
        for (int ks = 0; ks < 2; ++ks) {
            bf16x8 pb = *(const bf16x8*)&ovl.Pl[w][l15][ks * 32 + q * 8];
#pragma unroll
            for (int dt = 0; dt < 4; ++dt) {
                bf16x8 va = *(const bf16x8*)(Vbase + (size_t)(dt * 16 + l15) * 1024
                                             + jb + ks * 32 + q * 8);
                Oacc[dt] = __builtin_amdgcn_mfma_f32_16x16x32_bf16(va, pb, Oacc[dt], 0, 0, 0);
            }
        }
        __builtin_amdgcn_s_setprio(0);
    }

    lsum += __shfl_xor(lsum, 16);
    lsum += __shfl_xor(lsum, 32);

    __syncthreads();   // all K-loop Pl reads done before overlay reuse
    // round 1: waves 0..3 write their partials
    if (w < 4) {
#pragma unroll
        for (int dt = 0; dt < 4; ++dt)
#pragma unroll
            for (int r = 0; r < 4; ++r)
                ovl.post.Obuf[w][dt * 16 + q * 4 + r][l15] = Oacc[dt][r];
        if (lane < 16) ovl.post.lbuf[w][l15] = lsum;
    }
    __syncthreads();
    // round 2: waves 4..7 accumulate into slots 0..3
    if (w >= 4) {
#pragma unroll
        for (int dt = 0; dt < 4; ++dt)
#pragma unroll
            for (int r = 0; r < 4; ++r)
                ovl.post.Obuf[w - 4][dt * 16 + q * 4 + r][l15] += Oacc[dt][r];
        if (lane < 16) ovl.post.lbuf[w - 4][l15] += lsum;
    }
    __syncthreads();

    for (int t2 = tid; t2 < 1024; t2 += 512) {
        int il = t2 >> 6, d = t2 & 63;
        float o = ovl.post.Obuf[0][d][il] + ovl.post.Obuf[1][d][il]
                + ovl.post.Obuf[2][d][il] + ovl.post.Obuf[3][d][il];
        float l = ovl.post.lbuf[0][il] + ovl.post.lbuf[1][il]
                + ovl.post.lbuf[2][il] + ovl.post.lbuf[3][il];
        ao[((size_t)(b * 1024 + i0 + il)) * 512 + h * 64 + d] = f2bf(o / l);
    }
}

// ---------------------------------------------------------------------------
extern "C" void kernel_launch(void* const* d_in, const int* in_sizes, int n_in,
                              void* d_out, int out_size, void* d_ws, size_t ws_size,
                              hipStream_t stream)
{
    const float* x      = (const float*)d_in[0];
    const float* Wq     = (const float*)d_in[1];
    const float* Wk     = (const float*)d_in[2];
    const float* Wv     = (const float*)d_in[3];
    const float* Wo     = (const float*)d_in[4];
    const float* bo     = (const float*)d_in[5];
    const float* u_bias = (const float*)d_in[6];
    const float* v_bias = (const float*)d_in[7];
    const float* w_pos  = (const float*)d_in[8];
    float* out = (float*)d_out;

    char* ws = (char*)d_ws;
    unsigned short* Xbf  = (unsigned short*)ws;            ws += 3145728;
    unsigned short* Wqkv = (unsigned short*)ws;            ws += 2359296;
    unsigned short* Wob  = (unsigned short*)ws;            ws += 786432;
    unsigned short* Qbf  = (unsigned short*)ws;            ws += 2097152;
    unsigned short* Kbf  = (unsigned short*)ws;            ws += 2097152;
    unsigned short* Vtb  = (unsigned short*)ws;            ws += 2097152;
    unsigned short* aob  = (unsigned short*)ws;            ws += 2097152;
    float*          wsfx = (float*)ws;                     ws += 2048;
    unsigned char*  clsg = (unsigned char*)ws;             ws += 2048;

    pack_setup<<<3081, 256, 0, stream>>>(
        (const float4*)x, (const float4*)Wq, (const float4*)Wk,
        (const float4*)Wv, (const float4*)Wo,
        u_bias, v_bias, w_pos,
        (ushort4*)Xbf,
        (ushort4*)Wqkv, (ushort4*)Wqkv + 98304, (ushort4*)Wqkv + 196608,
        (ushort4*)Wob,
        wsfx, clsg);

    gemm_qkv<<<dim3(24, 32), 256, 0, stream>>>(Xbf, Wqkv, u_bias, Qbf, Kbf, Vtb);

    attn_mfma<<<dim3(64, 8, 2), 512, 0, stream>>>(
        Qbf, Kbf, Vtb, w_pos, wsfx, clsg, aob);

    gemm_o<<<dim3(12, 32), 256, 0, stream>>>(aob, Wob, bo, out);
}

// Round 10
// 132.651 us; speedup vs baseline: 1.0403x; 1.0403x over previous
//
#include <hip/hip_runtime.h>

#define LSEQ 1024
#define NB   2
#define NH   8
#define DD   64
#define DMOD 768

using bf16x8 = __attribute__((ext_vector_type(8))) short;
using f32x4  = __attribute__((ext_vector_type(4))) float;

__device__ inline unsigned short f2bf(float f) {
    union { float f; unsigned u; } v; v.f = f;
    unsigned r = v.u + 0x7FFFu + ((v.u >> 16) & 1u);
    return (unsigned short)(r >> 16);
}

// async global->LDS, 16B per lane. LDS dest is wave-uniform base + lane*16.
__device__ __forceinline__ void glds16(const unsigned short* g, unsigned short* l) {
    __builtin_amdgcn_global_load_lds(
        (const __attribute__((address_space(1))) void*)g,
        (__attribute__((address_space(3))) void*)l, 16, 0, 0);
}

// ---------------------------------------------------------------------------
// blocks 0..3071: pack x + Wq|Wk|Wv + Wo to bf16 (streaming)
// block  3072   : cls LUT (2048 u8)
// blocks 3073..3080: per-head wsfx[h][n] = (suffix(v.w_pos)-suffix(u.w_pos))/8
// ---------------------------------------------------------------------------
__global__ __launch_bounds__(256) void pack_setup(
    const float4* __restrict__ x,  const float4* __restrict__ wq,
    const float4* __restrict__ wk, const float4* __restrict__ wv,
    const float4* __restrict__ wo,
    const float* __restrict__ u_bias, const float* __restrict__ v_bias,
    const float* __restrict__ w_pos,
    ushort4* __restrict__ xb, ushort4* __restrict__ wqb, ushort4* __restrict__ wkb,
    ushort4* __restrict__ wvb, ushort4* __restrict__ wob,
    float* __restrict__ wsfx, unsigned char* __restrict__ cls_g)
{
    int tid = threadIdx.x;
    if (blockIdx.x >= 3072) {
        int sb = blockIdx.x - 3072;
        if (sb == 0) {
            // cls LUT
            __shared__ float w_s[32];
            __shared__ int cmin_s[1024];
            if (tid < 32) {
                float pr = expf(logf(512.5f) / 32.0f);
                w_s[tid] = powf(pr, (float)(tid + 1));
            }
            __syncthreads();
            for (int d = tid; d < 1024; d += 256) {
                float fd = (float)d;
                int cm = 32;
                for (int c = 31; c >= 0; --c) if (fd <= w_s[c]) cm = c;
                cmin_s[d] = cm;
            }
            __syncthreads();
            for (int d2 = tid; d2 < 2048; d2 += 256) {
                int dd = d2 - 1023;
                int ad = dd < 0 ? -dd : dd; if (ad > 1023) ad = 1023;
                int t = (dd < 0) ? 0 : ((dd == 0) ? 1 : 2);
                cls_g[d2] = (unsigned char)(t * 33 + cmin_s[ad]);
            }
        } else {
            // per-head wsfx
            int h = sb - 1;
            __shared__ float vred[4][64];
            __shared__ float ured[4][64];
            __shared__ float wd[64];
            int n = tid & 63, g = tid >> 6;
            float vs = 0.f, us = 0.f;
#pragma unroll
            for (int k = 0; k < 16; ++k) {
                int d = g * 16 + k;
                float wp = w_pos[(h * 64 + d) * 64 + n];
                vs += v_bias[h * 64 + d] * wp;
                us += u_bias[h * 64 + d] * wp;
            }
            vred[g][n] = vs; ured[g][n] = us;
            __syncthreads();
            if (tid < 64) {
                float v4 = vred[0][tid] + vred[1][tid] + vred[2][tid] + vred[3][tid];
                float u4 = ured[0][tid] + ured[1][tid] + ured[2][tid] + ured[3][tid];
                wd[tid] = v4 - u4;
            }
            __syncthreads();
            if (tid < 64) {
                int nn = tid & 31, cb = tid & 32;
                float s = 0.f;
                for (int c = 31; c >= nn; --c) s += wd[cb + c];
                wsfx[h * 64 + tid] = s * 0.125f;
            }
        }
        return;
    }
    int i = blockIdx.x * 256 + tid;
    const float4* src; ushort4* dst; int off;
    if (i < 393216)      { src = x;  dst = xb;  off = i; }
    else if (i < 491520) { src = wq; dst = wqb; off = i - 393216; }
    else if (i < 589824) { src = wk; dst = wkb; off = i - 491520; }
    else if (i < 688128) { src = wv; dst = wvb; off = i - 589824; }
    else                 { src = wo; dst = wob; off = i - 688128; }
    float4 v = src[off];
    ushort4 o;
    o.x = f2bf(v.x); o.y = f2bf(v.y); o.z = f2bf(v.z); o.w = f2bf(v.w);
    dst[off] = o;
}

// ---------------------------------------------------------------------------
// fused QKV projection GEMM: [2048x768] @ [1536x768]^T, 64x64 tile, 4 waves.
// Staging via global_load_lds width=16 with BOTH-SIDES XOR swizzle (rule #21).
// One barrier per K-step=64; next tile's DMA in flight under 8 MFMA/wave.
// ---------------------------------------------------------------------------
__global__ __launch_bounds__(256) void gemm_qkv(
    const unsigned short* __restrict__ X, const unsigned short* __restrict__ W,
    const float* __restrict__ ub,
    unsigned short* __restrict__ Qb, unsigned short* __restrict__ Kb,
    unsigned short* __restrict__ Vtb)
{
    __shared__ __align__(16) unsigned short Xs[2][64][64];
    __shared__ __align__(16) unsigned short Wsm[2][64][64];
    __shared__ __align__(16) unsigned short Ct[64][72];

    int tid = threadIdx.x;
    int w = tid >> 6, lane = tid & 63, l15 = lane & 15, q = lane >> 4;
    int M0 = blockIdx.y * 64, N0 = blockIdx.x * 64;

    int sr = lane >> 3;                        // == dest row & 7
    int scol = ((lane & 7) * 8) ^ (sr << 3);   // shorts
    const unsigned short* xg = X + (size_t)(M0 + w * 8 + sr) * 768 + scol;
    const unsigned short* wg = W + (size_t)(N0 + w * 8 + sr) * 768 + scol;
    unsigned short* XsF = &Xs[0][0][0];
    unsigned short* WsF = &Wsm[0][0][0];
    int wb = w * 512;   // wave-uniform LDS short offset

#define ISSUE(K, BUF) do { \
    glds16(xg + (K),             XsF + (BUF) * 4096 + wb); \
    glds16(xg + 32 * 768 + (K),  XsF + (BUF) * 4096 + 2048 + wb); \
    glds16(wg + (K),             WsF + (BUF) * 4096 + wb); \
    glds16(wg + 32 * 768 + (K),  WsF + (BUF) * 4096 + 2048 + wb); \
} while (0)

    ISSUE(0, 0);

    int rswz = (l15 & 7) << 3;                 // read-side XOR (shorts)
    f32x4 acc[4] = {};
    int cur = 0;
    for (int k0 = 0; k0 < 768; k0 += 64) {
        __syncthreads();                 // vmcnt drain -> buf[cur] ready
        if (k0 + 64 < 768) ISSUE(k0 + 64, cur ^ 1);   // async, hides under MFMA
        bf16x8 a0 = *(bf16x8*)&Xs[cur][w * 16 + l15][(q * 8) ^ rswz];
        bf16x8 a1 = *(bf16x8*)&Xs[cur][w * 16 + l15][(32 + q * 8) ^ rswz];
#pragma unroll
        for (int ct = 0; ct < 4; ++ct) {
            bf16x8 b0 = *(bf16x8*)&Wsm[cur][ct * 16 + l15][(q * 8) ^ rswz];
            bf16x8 b1 = *(bf16x8*)&Wsm[cur][ct * 16 + l15][(32 + q * 8) ^ rswz];
            acc[ct] = __builtin_amdgcn_mfma_f32_16x16x32_bf16(a0, b0, acc[ct], 0, 0, 0);
            acc[ct] = __builtin_amdgcn_mfma_f32_16x16x32_bf16(a1, b1, acc[ct], 0, 0, 0);
        }
        cur ^= 1;
    }
#undef ISSUE

    if (N0 < 1024) {
        int isQ = (N0 < 512);
#pragma unroll
        for (int ct = 0; ct < 4; ++ct) {
            float u0 = isQ ? ub[N0 + ct * 16 + l15] : 0.f;
            float sc = isQ ? 0.125f : 1.0f;
#pragma unroll
            for (int r = 0; r < 4; ++r)
                Ct[w * 16 + q * 4 + r][ct * 16 + l15] = f2bf((acc[ct][r] + u0) * sc);
        }
        __syncthreads();
        int Nh = isQ ? N0 : (N0 - 512);
        unsigned short* out = isQ ? Qb : Kb;
        size_t base = ((size_t)((M0 >> 10) * 8 + (Nh >> 6)) * 1024 + (M0 & 1023)) * 64;
#pragma unroll
        for (int it = 0; it < 2; ++it) {
            int idx = tid + it * 256;
            int row = idx >> 3, sg = idx & 7;
            *(uint4*)(out + base + (size_t)row * 64 + sg * 8) = *(uint4*)&Ct[row][sg * 8];
        }
    } else {
#pragma unroll
        for (int ct = 0; ct < 4; ++ct) {
            ushort4 pk;
            pk.x = f2bf(acc[ct][0]); pk.y = f2bf(acc[ct][1]);
            pk.z = f2bf(acc[ct][2]); pk.w = f2bf(acc[ct][3]);
            *(ushort4*)&Ct[ct * 16 + l15][w * 16 + q * 4] = pk;   // [d][j]
        }
        __syncthreads();
        size_t base = ((size_t)((M0 >> 10) * 8 + ((N0 - 1024) >> 6))) * 65536;
        int j0 = M0 & 1023;
#pragma unroll
        for (int it = 0; it < 2; ++it) {
            int idx = tid + it * 256;
            int d = idx >> 3, sg = idx & 7;
            *(uint4*)(Vtb + base + (size_t)d * 1024 + j0 + sg * 8) = *(uint4*)&Ct[d][sg * 8];
        }
    }
}

// ---------------------------------------------------------------------------
// out-projection GEMM: fp32 out [2048][768] = aob[2048][512] @ Wo[768][512]^T
// + bo. Same swizzled global_load_lds staging, K-step 64, 8 iterations.
// ---------------------------------------------------------------------------
__global__ __launch_bounds__(256) void gemm_o(
    const unsigned short* __restrict__ X, const unsigned short* __restrict__ W,
    const float* __restrict__ bias, float* __restrict__ out)
{
    __shared__ __align__(16) unsigned short Xs[2][64][64];
    __shared__ __align__(16) unsigned short Wsm[2][64][64];
    __shared__ __align__(16) float Ctf[64][72];

    int tid = threadIdx.x;
    int w = tid >> 6, lane = tid & 63, l15 = lane & 15, q = lane >> 4;
    int M0 = blockIdx.y * 64, N0 = blockIdx.x * 64;

    int sr = lane >> 3;
    int scol = ((lane & 7) * 8) ^ (sr << 3);
    const unsigned short* xg = X + (size_t)(M0 + w * 8 + sr) * 512 + scol;
    const unsigned short* wg = W + (size_t)(N0 + w * 8 + sr) * 512 + scol;
    unsigned short* XsF = &Xs[0][0][0];
    unsigned short* WsF = &Wsm[0][0][0];
    int wb = w * 512;

#define ISSUEO(K, BUF) do { \
    glds16(xg + (K),             XsF + (BUF) * 4096 + wb); \
    glds16(xg + 32 * 512 + (K),  XsF + (BUF) * 4096 + 2048 + wb); \
    glds16(wg + (K),             WsF + (BUF) * 4096 + wb); \
    glds16(wg + 32 * 512 + (K),  WsF + (BUF) * 4096 + 2048 + wb); \
} while (0)

    ISSUEO(0, 0);

    int rswz = (l15 & 7) << 3;
    f32x4 acc[4] = {};
    int cur = 0;
    for (int k0 = 0; k0 < 512; k0 += 64) {
        __syncthreads();
        if (k0 + 64 < 512) ISSUEO(k0 + 64, cur ^ 1);
        bf16x8 a0 = *(bf16x8*)&Xs[cur][w * 16 + l15][(q * 8) ^ rswz];
        bf16x8 a1 = *(bf16x8*)&Xs[cur][w * 16 + l15][(32 + q * 8) ^ rswz];
#pragma unroll
        for (int ct = 0; ct < 4; ++ct) {
            bf16x8 b0 = *(bf16x8*)&Wsm[cur][ct * 16 + l15][(q * 8) ^ rswz];
            bf16x8 b1 = *(bf16x8*)&Wsm[cur][ct * 16 + l15][(32 + q * 8) ^ rswz];
            acc[ct] = __builtin_amdgcn_mfma_f32_16x16x32_bf16(a0, b0, acc[ct], 0, 0, 0);
            acc[ct] = __builtin_amdgcn_mfma_f32_16x16x32_bf16(a1, b1, acc[ct], 0, 0, 0);
        }
        cur ^= 1;
    }
#undef ISSUEO

#pragma unroll
    for (int ct = 0; ct < 4; ++ct) {
        float bv = bias[N0 + ct * 16 + l15];
#pragma unroll
        for (int r = 0; r < 4; ++r)
            Ctf[w * 16 + q * 4 + r][ct * 16 + l15] = acc[ct][r] + bv;
    }
    __syncthreads();
#pragma unroll
    for (int it = 0; it < 4; ++it) {
        int idx = tid + it * 256;
        int row = idx >> 4, sg = idx & 15;
        *(float4*)(out + (size_t)(M0 + row) * 768 + N0 + sg * 4) = *(float4*)&Ctf[row][sg * 4];
    }
}

// ---------------------------------------------------------------------------
// MFMA flash attention with fused qr-bias computation (R7-exact, best
// measured 132.65). 256 thr / 4 waves, each wave a j-quarter, no barriers
// in the K-loop. cvt_pk P-pack (RNE == f2bf), 4-way lsum chains, cls gather
// via 2 aligned b32 + funnel shift. T5 setprio around MFMA clusters.
// NOTE: 8-wave/512-thr variant (R9) measured 138.0 — occupancy-doubling
// regresses here (phase-synchronized waves contend on shared L1/L2 queues).
// ---------------------------------------------------------------------------
__global__ __launch_bounds__(256, 4) void attn_mfma(
    const unsigned short* __restrict__ Qbf,   // [bh][i][d] bf16 ((q+u)/8)
    const unsigned short* __restrict__ Kbf,   // [bh][j][d] bf16
    const unsigned short* __restrict__ Vt,    // [bh][d][j] bf16
    const float* __restrict__ w_pos,          // [h][d][n] fp32
    const float* __restrict__ wsfx,           // [h][64]  (vsfx-usfx)/8
    const unsigned char* __restrict__ cls_g,
    unsigned short* __restrict__ ao)          // [b*1024+i][h*64+d] bf16
{
    __shared__ float biasT[16 * 99];
    __shared__ __align__(4) unsigned char cls[2048];
    __shared__ unsigned short Pl[4][16][76];
    union Ovl {
        struct { unsigned short wptS[64][68]; float qwL[16][68]; } pre;
        struct { float Obuf[4][64][17]; float lbuf[4][16]; } post;
    };
    __shared__ Ovl ovl;

    int tid = threadIdx.x;
    int b = blockIdx.z, h = blockIdx.y, bh = b * 8 + h;
    int i0 = blockIdx.x * 16;
    int w = tid >> 6, lane = tid & 63, l15 = lane & 15, q = lane >> 4;

    for (int idx = tid; idx < 512; idx += 256)
        ((unsigned int*)cls)[idx] = ((const unsigned int*)cls_g)[idx];
    // stage w_pos[h] (fp32 [d][n]) -> bf16 transposed wptS[n][d], padded rows
    {
        const float4* wsrc = (const float4*)(w_pos + h * 4096);
#pragma unroll
        for (int it = 0; it < 4; ++it) {
            int f = tid + it * 256;          // float4 index, 0..1023
            float4 wv = wsrc[f];
            int d = f >> 4, n4 = (f & 15) * 4;
            ovl.pre.wptS[n4 + 0][d] = f2bf(wv.x);
            ovl.pre.wptS[n4 + 1][d] = f2bf(wv.y);
            ovl.pre.wptS[n4 + 2][d] = f2bf(wv.z);
            ovl.pre.wptS[n4 + 3][d] = f2bf(wv.w);
        }
    }

    int ig = i0 + l15;
    const unsigned short* qrow = Qbf + ((size_t)bh * 1024 + ig) * 64;
    bf16x8 qf0 = *(const bf16x8*)(qrow + q * 8);
    bf16x8 qf1 = *(const bf16x8*)(qrow + 32 + q * 8);
    __syncthreads();

    // qw MFMA: wave w covers n = w*16 .. w*16+15
    {
        bf16x8 b0 = *(bf16x8*)&ovl.pre.wptS[w * 16 + l15][q * 8];
        bf16x8 b1 = *(bf16x8*)&ovl.pre.wptS[w * 16 + l15][32 + q * 8];
        f32x4 a = {};
        a = __builtin_amdgcn_mfma_f32_16x16x32_bf16(qf0, b0, a, 0, 0, 0);
        a = __builtin_amdgcn_mfma_f32_16x16x32_bf16(qf1, b1, a, 0, 0, 0);
#pragma unroll
        for (int r = 0; r < 4; ++r)
            ovl.pre.qwL[q * 4 + r][w * 16 + l15] = a[r];
    }
    __syncthreads();

    // suffix-scan halves (fixed 32 iters, broadcast reads) + add wsfx, in-place
    const float* wsh = wsfx + h * 64;
#pragma unroll
    for (int it = 0; it < 4; ++it) {
        int idx = tid + it * 256;
        int il = idx >> 6, n = idx & 63, nn = n & 31, cb = n & 32;
        float run = 0.f, s = 0.f;
#pragma unroll
        for (int c = 31; c >= 0; --c) {
            run += ovl.pre.qwL[il][cb + c];
            if (c == nn) s = run;
        }
        ovl.pre.qwL[il][n] = s + wsh[n];
    }
    __syncthreads();

    for (int idx = tid; idx < 528; idx += 256) {
        int il = idx / 33, c = idx - il * 33;
        float up = 0.f, sp = 0.f;
        if (c < 32) {
            up = ovl.pre.qwL[il][c];
            sp = ovl.pre.qwL[il][32 + c];
        }
        float* bt = biasT + il * 99;
        bt[c]      = up - sp;   // dd < 0
        bt[33 + c] = up;        // dd == 0
        bt[66 + c] = up + sp;   // dd > 0
    }
    __syncthreads();

    const unsigned short* Kbase = Kbf + (size_t)bh * 65536;
    const unsigned short* Vbase = Vt  + (size_t)bh * 65536;
    const float* btrow = biasT + l15 * 99;
    int clsoff = 1023 - ig;

    f32x4 Oacc[4] = {};
    float ls0 = 0.f, ls1 = 0.f, ls2 = 0.f, ls3 = 0.f;

    for (int jt = 0; jt < 4; ++jt) {
        int jb = w * 256 + jt * 64;
        f32x4 st[4];
        __builtin_amdgcn_s_setprio(1);
#pragma unroll
        for (int ct = 0; ct < 4; ++ct) {
            const unsigned short* krow = Kbase + (size_t)(jb + ct * 16 + l15) * 64;
            bf16x8 ka0 = *(const bf16x8*)(krow + q * 8);
            bf16x8 ka1 = *(const bf16x8*)(krow + 32 + q * 8);
            f32x4 a = {};
            a = __builtin_amdgcn_mfma_f32_16x16x32_bf16(ka0, qf0, a, 0, 0, 0);
            a = __builtin_amdgcn_mfma_f32_16x16x32_bf16(ka1, qf1, a, 0, 0, 0);
            st[ct] = a;
        }
        __builtin_amdgcn_s_setprio(0);
#pragma unroll
        for (int ct = 0; ct < 4; ++ct) {
            int d2b = jb + ct * 16 + q * 4 + clsoff;
            int cbase = d2b & ~3, sh = (d2b & 3) * 8;
            unsigned c0 = *(const unsigned*)&cls[cbase];
            unsigned c1 = *(const unsigned*)&cls[cbase + 4];
            unsigned word = (unsigned)(((((unsigned long long)c1) << 32) | c0) >> sh);
            float p0 = __expf(st[ct][0] + btrow[word & 0xffu]);
            float p1 = __expf(st[ct][1] + btrow[(word >> 8) & 0xffu]);
            float p2 = __expf(st[ct][2] + btrow[(word >> 16) & 0xffu]);
            float p3 = __expf(st[ct][3] + btrow[word >> 24]);
            ls0 += p0; ls1 += p1; ls2 += p2; ls3 += p3;
            unsigned lo, hi;
            asm("v_cvt_pk_bf16_f32 %0, %1, %2" : "=v"(lo) : "v"(p0), "v"(p1));
            asm("v_cvt_pk_bf16_f32 %0, %1, %2" : "=v"(hi) : "v"(p2), "v"(p3));
            uint2 pk2; pk2.x = lo; pk2.y = hi;
            *(uint2*)&Pl[w][l15][ct * 16 + q * 4] = pk2;
        }
        __builtin_amdgcn_s_setprio(1);
#pragma unroll
        for (int ks = 0; ks < 2; ++ks) {
            bf16x8 pb = *(const bf16x8*)&Pl[w][l15][ks * 32 + q * 8];
#pragma unroll
            for (int dt = 0; dt < 4; ++dt) {
                bf16x8 va = *(const bf16x8*)(Vbase + (size_t)(dt * 16 + l15) * 1024
                                             + jb + ks * 32 + q * 8);
                Oacc[dt] = __builtin_amdgcn_mfma_f32_16x16x32_bf16(va, pb, Oacc[dt], 0, 0, 0);
            }
        }
        __builtin_amdgcn_s_setprio(0);
    }

    float lsum = (ls0 + ls1) + (ls2 + ls3);
    lsum += __shfl_xor(lsum, 16);
    lsum += __shfl_xor(lsum, 32);

    __syncthreads();   // all preamble/K-loop reads done before overlay reuse
#pragma unroll
    for (int dt = 0; dt < 4; ++dt)
#pragma unroll
        for (int r = 0; r < 4; ++r)
            ovl.post.Obuf[w][dt * 16 + q * 4 + r][l15] = Oacc[dt][r];
    if (lane < 16) ovl.post.lbuf[w][l15] = lsum;
    __syncthreads();

    for (int t2 = tid; t2 < 1024; t2 += 256) {
        int il = t2 >> 6, d = t2 & 63;
        float o = ovl.post.Obuf[0][d][il] + ovl.post.Obuf[1][d][il]
                + ovl.post.Obuf[2][d][il] + ovl.post.Obuf[3][d][il];
        float l = ovl.post.lbuf[0][il] + ovl.post.lbuf[1][il]
                + ovl.post.lbuf[2][il] + ovl.post.lbuf[3][il];
        ao[((size_t)(b * 1024 + i0 + il)) * 512 + h * 64 + d] = f2bf(o / l);
    }
}

// ---------------------------------------------------------------------------
extern "C" void kernel_launch(void* const* d_in, const int* in_sizes, int n_in,
                              void* d_out, int out_size, void* d_ws, size_t ws_size,
                              hipStream_t stream)
{
    const float* x      = (const float*)d_in[0];
    const float* Wq     = (const float*)d_in[1];
    const float* Wk     = (const float*)d_in[2];
    const float* Wv     = (const float*)d_in[3];
    const float* Wo     = (const float*)d_in[4];
    const float* bo     = (const float*)d_in[5];
    const float* u_bias = (const float*)d_in[6];
    const float* v_bias = (const float*)d_in[7];
    const float* w_pos  = (const float*)d_in[8];
    float* out = (float*)d_out;

    char* ws = (char*)d_ws;
    unsigned short* Xbf  = (unsigned short*)ws;            ws += 3145728;
    unsigned short* Wqkv = (unsigned short*)ws;            ws += 2359296;
    unsigned short* Wob  = (unsigned short*)ws;            ws += 786432;
    unsigned short* Qbf  = (unsigned short*)ws;            ws += 2097152;
    unsigned short* Kbf  = (unsigned short*)ws;            ws += 2097152;
    unsigned short* Vtb  = (unsigned short*)ws;            ws += 2097152;
    unsigned short* aob  = (unsigned short*)ws;            ws += 2097152;
    float*          wsfx = (float*)ws;                     ws += 2048;
    unsigned char*  clsg = (unsigned char*)ws;             ws += 2048;

    pack_setup<<<3081, 256, 0, stream>>>(
        (const float4*)x, (const float4*)Wq, (const float4*)Wk,
        (const float4*)Wv, (const float4*)Wo,
        u_bias, v_bias, w_pos,
        (ushort4*)Xbf,
        (ushort4*)Wqkv, (ushort4*)Wqkv + 98304, (ushort4*)Wqkv + 196608,
        (ushort4*)Wob,
        wsfx, clsg);

    gemm_qkv<<<dim3(24, 32), 256, 0, stream>>>(Xbf, Wqkv, u_bias, Qbf, Kbf, Vtb);

    attn_mfma<<<dim3(64, 8, 2), 256, 0, stream>>>(
        Qbf, Kbf, Vtb, w_pos, wsfx, clsg, aob);

    gemm_o<<<dim3(12, 32), 256, 0, stream>>>(aob, Wob, bo, out);
}